// Round 2
// 598.698 us; speedup vs baseline: 1.0183x; 1.0183x over previous
//
#include <hip/hip_runtime.h>
#include <stdint.h>

// ---------------------------------------------------------------------------
// SpatialConvModule: 4-direction spatial propagation (SCNN-like) + fusion GEMM
//   R6: R4 launch shape (160 x 512, proven-resident) + depth-2 x prefetch.
//   - x(i+2) issued at step t, consumed at t+1 => load latency covered by a
//     full step period (R4 covered only ~1/3 step; one block's HBM miss
//     propagated through the lockstep network to every block's period).
//   - Publish boundary rows immediately after epilogue; early neighbor probe
//     overlaps the first poll's latency with the LDS s-build.
//   - fp32 xT retained (bit-identical numerics to the verified R4 run).
// ---------------------------------------------------------------------------

typedef __attribute__((ext_vector_type(8))) __bf16 bf16x8;
typedef __attribute__((ext_vector_type(4))) float f32x4;

#define DEV static __device__ __forceinline__

DEV unsigned short f2bf(float f) {
  union { float f; unsigned int u; } v; v.f = f;
  unsigned int u = v.u;
  u += 0x7fffu + ((u >> 16) & 1u);   // round-to-nearest-even
  return (unsigned short)(u >> 16);
}
DEV float bf2f(unsigned short s) {
  union { float f; unsigned int u; } v; v.u = ((unsigned int)s) << 16;
  return v.f;
}
DEV f32x4 mfma16(bf16x8 a, bf16x8 b, f32x4 c) {
  return __builtin_amdgcn_mfma_f32_16x16x32_bf16(a, b, c, 0, 0, 0);
}
// LDS-only barrier: does NOT drain vmcnt (global loads/stores stay in flight).
DEV void barrier_lds() {
  asm volatile("s_waitcnt lgkmcnt(0)\n\ts_barrier" ::: "memory");
}

constexpr int Hc = 160, Wc = 160, Cc = 128;
constexpr int CHUNK = 16, NCH = 10;  // 10 chunks of 16 along the inner axis
constexpr int ROWS = 18;             // u0-1 .. u0+16 (halo top/bottom)
constexpr int SPAD = 136;            // sT row stride in bf16

// workspace layout (bytes)
constexpr long WS_XT    = 0;                         // fp32 [8][160][160][128] = 104857600
constexpr long WS_WPREP = 104857600;                 // bf16 [4][128][384]      = 393216
constexpr long WS_EPI   = 105250816;                 // float2 [512]            = 4096
constexpr long WS_FWT   = 105254912;                 // bf16 [128][512]         = 131072
constexpr long WS_FEPI  = 105385984;                 // float2 [128]            = 1024
constexpr long WS_FEAT  = 105387008;                 // bf16 [8][160][160][512] = 209715200
constexpr long WS_EX    = 315102208;                 // u32 [320][2][2][128]    = 655360
constexpr long WS_TOTAL = 315757568;

// ---------------------------------------------------------------------------
__global__ void prep_kernel(const float* __restrict__ kern, const float* __restrict__ bias,
                            const float* __restrict__ bg, const float* __restrict__ bb,
                            const float* __restrict__ bm, const float* __restrict__ bv,
                            const float* __restrict__ fw, const float* __restrict__ fb2,
                            const float* __restrict__ fg, const float* __restrict__ fbt,
                            const float* __restrict__ fm, const float* __restrict__ fv,
                            unsigned short* __restrict__ wprep, float2* __restrict__ epi,
                            unsigned short* __restrict__ fwT, float2* __restrict__ fepi)
{
  int idx = blockIdx.x * 256 + threadIdx.x;
  if (idx < 196608) {                 // wprep[d][o][t*128+c] = kmid[d][o][c][t]
    int c = idx & 127;
    int t = (idx >> 7) % 3;
    int o = (idx / 384) & 127;
    int d = idx / 49152;
    int kh = (d < 2) ? 1 : t;         // rows use k[:,:,1,:], cols use k[:,:,:,1]
    int kw = (d < 2) ? t : 1;
    wprep[idx] = f2bf(kern[(((d * 128 + o) * 128 + c) * 3 + kh) * 3 + kw]);
  }
  int i2 = idx - 196608;              // fusion weights [o][d*128+c] -> bf16
  if (i2 >= 0 && i2 < 65536) fwT[i2] = f2bf(fw[i2]);
  int i3 = idx - 262144;              // per-(d,o) BN fold: y = conv*scale + shift
  if (i3 >= 0 && i3 < 512) {
    float sc = bg[i3] / sqrtf(bv[i3] + 1e-5f);
    epi[i3] = make_float2(sc, (bias[i3] - bm[i3]) * sc + bb[i3]);
  }
  int i4 = idx - 262656;              // fusion BN fold
  if (i4 >= 0 && i4 < 128) {
    float sc = fg[i4] / sqrtf(fv[i4] + 1e-5f);
    fepi[i4] = make_float2(sc, (fb2[i4] - fm[i4]) * sc + fbt[i4]);
  }
}

// ---------------------------------------------------------------------------
__global__ void transpose_kernel(const float* __restrict__ x, float* __restrict__ xT)
{
  __shared__ float tile[32][33];
  int b = blockIdx.z, h = blockIdx.y;
  int c0 = (blockIdx.x / 5) * 32, w0 = (blockIdx.x % 5) * 32;
  int tx = threadIdx.x & 31, ty = threadIdx.x >> 5;
#pragma unroll
  for (int r = 0; r < 4; r++) {
    int c = c0 + ty + 8 * r;
    tile[ty + 8 * r][tx] = x[(((long)b * 128 + c) * 160 + h) * 160 + w0 + tx];
  }
  __syncthreads();
#pragma unroll
  for (int r = 0; r < 4; r++) {
    int w = w0 + ty + 8 * r;
    xT[(((long)b * 160 + h) * 160 + w) * 128 + c0 + tx] = tile[tx][ty + 8 * r];
  }
}

// ---------------------------------------------------------------------------
// One scan step. PAR is the compile-time parity (t&1). XC/XHC hold x(i(t+1))
// loaded during the PREVIOUS step; XN/XHN receive the prefetch of x(i(t+2)).
#define SCAN_STEP(T, PAR, XC, XHC, XN, XHN)                                     \
  do {                                                                          \
    const int t_ = (T);                                                         \
    const int i_ = rev ? (159 - t_) : t_;                                       \
    const bool last_ = (t_ == 159);                                             \
    const unsigned short* cur_ = sbuf[s][PAR];                                  \
    unsigned short* nxt_ = sbuf[s][(PAR) ^ 1];                                  \
    /* prefetch x(i(t+2)) — consumed NEXT step (one full period of cover) */    \
    if (t_ < 158) {                                                             \
      const float* xr2_ = xb + (long)(rev ? (i_ - 2) : (i_ + 2)) * si;          \
      _Pragma("unroll") for (int j = 0; j < 2; j++)                             \
        _Pragma("unroll") for (int r = 0; r < 4; r++)                           \
          XN[j][r] = xr2_[xoff[j][r]];                                          \
      if (ug_ok) XHN = xr2_[xhoff];                                             \
    }                                                                           \
    /* MFMA: D[m][n=o] = sum_k s[m-1+t][c] * w[o][t*128+c]  (M=16 tile) */      \
    f32x4 acc0_ = {0.f, 0.f, 0.f, 0.f}, acc1_ = {0.f, 0.f, 0.f, 0.f};           \
    _Pragma("unroll") for (int kt = 0; kt < 12; kt++) {                         \
      const int tt_ = kt >> 2;                                                  \
      const int cc_ = ((kt & 3) << 5) + (kq << 3);                              \
      const bf16x8 A0_ = *(const bf16x8*)&cur_[(ncol + tt_) * SPAD + cc_];      \
      acc0_ = mfma16(A0_, Bfrag[0][kt], acc0_);                                 \
      acc1_ = mfma16(A0_, Bfrag[1][kt], acc1_);                                 \
    }                                                                           \
    /* epilogue: BN fold + PReLU */                                             \
    float yf_[2][4];                                                            \
    unsigned short yb_[2][4];                                                   \
    _Pragma("unroll") for (int r = 0; r < 4; r++) {                             \
      float v0_ = acc0_[r] * ep[0].x + ep[0].y;                                 \
      v0_ = (v0_ >= 0.f) ? v0_ : (aslope * v0_);                                \
      yf_[0][r] = v0_; yb_[0][r] = f2bf(v0_);                                   \
      float v1_ = acc1_[r] * ep[1].x + ep[1].y;                                 \
      v1_ = (v1_ >= 0.f) ? v1_ : (aslope * v1_);                                \
      yf_[1][r] = v1_; yb_[1][r] = f2bf(v1_);                                   \
    }                                                                           \
    /* publish boundary rows ASAP: word = (t+1)<<16 | bf16(y) */                \
    {                                                                           \
      const unsigned int tagv_ = ((unsigned int)(t_ + 1)) << 16;                \
      if (kq == 0) {                                                            \
        __hip_atomic_store(&ex_self[(PAR) * 128 + colj[0]],                     \
                           tagv_ | (unsigned int)yb_[0][0],                     \
                           __ATOMIC_RELAXED, __HIP_MEMORY_SCOPE_AGENT);         \
        __hip_atomic_store(&ex_self[(PAR) * 128 + colj[1]],                     \
                           tagv_ | (unsigned int)yb_[1][0],                     \
                           __ATOMIC_RELAXED, __HIP_MEMORY_SCOPE_AGENT);         \
      }                                                                         \
      if (kq == 3) {                                                            \
        __hip_atomic_store(&ex_self[256 + (PAR) * 128 + colj[0]],               \
                           tagv_ | (unsigned int)yb_[0][3],                     \
                           __ATOMIC_RELAXED, __HIP_MEMORY_SCOPE_AGENT);         \
        __hip_atomic_store(&ex_self[256 + (PAR) * 128 + colj[1]],               \
                           tagv_ | (unsigned int)yb_[1][3],                     \
                           __ATOMIC_RELAXED, __HIP_MEMORY_SCOPE_AGENT);         \
      }                                                                         \
    }                                                                           \
    /* early probe of neighbor slot (usually already published) */              \
    unsigned int hv_ = 0;                                                       \
    if (!last_ && interior)                                                     \
      hv_ = __hip_atomic_load(ex_nbr + (PAR) * 128 + oh,                        \
                              __ATOMIC_RELAXED, __HIP_MEMORY_SCOPE_AGENT);      \
    /* s(t+1) interior rows: consume PREVIOUS step's prefetch (XC) */           \
    if (!last_) {                                                               \
      _Pragma("unroll") for (int j = 0; j < 2; j++)                             \
        _Pragma("unroll") for (int r = 0; r < 4; r++)                           \
          nxt_[(1 + kq * 4 + r) * SPAD + colj[j]] =                             \
              f2bf(XC[j][r] + yf_[j][r]);                                       \
    }                                                                           \
    /* feat store (fire-and-forget vmem, off LDS critical path) */              \
    {                                                                           \
      unsigned short* frow_ = fbp + (long)i_ * fi;                              \
      _Pragma("unroll") for (int j = 0; j < 2; j++)                             \
        _Pragma("unroll") for (int r = 0; r < 4; r++)                           \
          frow_[foff[j][r]] = yb_[j][r];                                        \
    }                                                                           \
    /* halo fill from neighbor (tagged spin; mutual coupling bounds skew) */    \
    if (!last_) {                                                               \
      float yv_ = 0.f;                                                          \
      if (interior) {                                                           \
        const unsigned int* slot_ = ex_nbr + (PAR) * 128 + oh;                  \
        unsigned int v_ = hv_;                                                  \
        while ((v_ >> 16) != (unsigned int)(t_ + 1)) {                          \
          __builtin_amdgcn_s_sleep(1);                                          \
          v_ = __hip_atomic_load(slot_, __ATOMIC_RELAXED,                       \
                                 __HIP_MEMORY_SCOPE_AGENT);                     \
        }                                                                       \
        yv_ = bf2f((unsigned short)(v_ & 0xffffu));                             \
      }                                                                         \
      unsigned short sv_ = 0;                                                   \
      if (ug_ok) sv_ = f2bf(XHC + yv_);                                         \
      nxt_[srow * SPAD + oh] = sv_;                                             \
    }                                                                           \
    barrier_lds();  /* s(t+1) complete; vmem (feat, prefetch) stays in flight */\
  } while (0)

// scan: bid = q*16 + (p*8+b); bid%8 invariant over q => chain stays on one XCD.
// 512 threads: waves 0-3 = stream 0 (d=2p), waves 4-7 = stream 1 (d=2p+1).
__global__ __launch_bounds__(512, 2) void scan_kernel(
    const float* __restrict__ xT, const unsigned short* __restrict__ wprep,
    const float2* __restrict__ epi, const float* __restrict__ prelu_a,
    unsigned short* __restrict__ featbuf, unsigned int* __restrict__ ex)
{
  __shared__ __align__(16) unsigned short sbuf[2][2][ROWS * SPAD];  // [stream][parity]

  const int bid = blockIdx.x;
  const int q = bid >> 4;            // chunk 0..9
  const int g = bid & 15;            // p*8 + b
  const int p = g >> 3, b = g & 7;   // p: 0=row-mode(d0,d1), 1=col-mode(d2,d3)
  const int tid = threadIdx.x;
  const int wv = tid >> 6;           // wave 0..7
  const int s = wv >> 2;             // stream 0/1 within block
  const int wl = wv & 3;             // wave-in-stream: n-tiles {2wl, 2wl+1}
  const int lane = tid & 63;
  const int ncol = lane & 15;        // A-row / B-col / D-col lane index
  const int kq = lane >> 4;          // k-quad / D-row-quad
  const int d = p * 2 + s;
  const bool rev = (s != 0);
  const int u0 = q * CHUNK;

  const bool row_mode = (p == 0);
  const long si = row_mode ? (long)Wc * Cc : (long)Cc;   // scan-axis stride in xT
  const int  su = row_mode ? Cc : Wc * Cc;               // inner-axis stride in xT
  const long fi = row_mode ? (long)Wc * 512 : (long)512; // scan-axis stride in feat
  const int  fu = row_mode ? 512 : Wc * 512;             // inner-axis stride in feat
  const float* xb = xT + (long)b * Hc * Wc * Cc;
  unsigned short* fbp = featbuf + (long)b * Hc * Wc * 512 + d * 128;

  // B fragments: registers for all 160 steps. B[k=t*128+c][n=o].
  bf16x8 Bfrag[2][12];
  float2 ep[2];
  int colj[2];
#pragma unroll
  for (int j = 0; j < 2; j++) {
    const int o = (wl * 2 + j) * 16 + ncol;
    colj[j] = o;
    const unsigned short* wp = wprep + ((long)(d * 128 + o)) * 384;
#pragma unroll
    for (int kt = 0; kt < 12; kt++)
      Bfrag[j][kt] = *(const bf16x8*)(wp + kt * 32 + kq * 8);
    ep[j] = epi[d * 128 + o];
  }
  const float aslope = prelu_a[d];

  // loop-invariant per-cell offsets (element units, fit in 32-bit)
  int xoff[2][4], foff[2][4];
#pragma unroll
  for (int j = 0; j < 2; j++)
#pragma unroll
    for (int r = 0; r < 4; r++) {
      const int row = kq * 4 + r;
      xoff[j][r] = (u0 + row) * su + colj[j];
      foff[j][r] = (u0 + row) * fu + colj[j];
    }

  // exchange: sid = d*80 + b*10 + q; layout [sid][side][par][128]
  const int sid = d * 80 + b * 10 + q;
  unsigned int* ex_self = ex + (long)sid * 512;

  // halo thread mapping: each of the 512 threads owns one (stream, side, ch)
  const int hside = (tid >> 7) & 1;          // 0 = low (u0-1), 1 = high (u0+16)
  const int oh = tid & 127;
  const bool interior = hside ? (q < NCH - 1) : (q > 0);
  const int ug = hside ? (u0 + CHUNK) : (u0 - 1);
  const bool ug_ok = (ug >= 0 && ug < 160);
  const int srow = hside ? (ROWS - 1) : 0;
  const int xhoff = ug_ok ? (ug * su + oh) : 0;
  const unsigned int* ex_nbr = hside ? (ex + (long)(sid + 1) * 512)
                                     : (ex + (long)(sid - 1) * 512 + 256);

  // prologue: s(t=0) = x(i0) into sbuf[s][0]
  const int i0 = rev ? (Hc - 1) : 0;
  const int tids = tid & 255;
  for (int e = tids; e < ROWS * 64; e += 256) {
    const int u = e >> 6, cp = e & 63;
    const int uu = u0 + u - 1;
    unsigned int sv = 0;
    if (uu >= 0 && uu < 160) {
      const float2 xv2 = *(const float2*)(xb + (long)i0 * si + (long)uu * su + cp * 2);
      sv = (unsigned int)f2bf(xv2.x) | ((unsigned int)f2bf(xv2.y) << 16);
    }
    *(unsigned int*)&sbuf[s][0][u * SPAD + cp * 2] = sv;
  }

  // preload x(i(1)) into buffer A (consumed at t=0)
  float xcA[2][4], xcB[2][4];
  float xhA = 0.f, xhB = 0.f;
  {
    const float* xrow = xb + (long)(rev ? (Hc - 2) : 1) * si;
#pragma unroll
    for (int j = 0; j < 2; j++)
#pragma unroll
      for (int r = 0; r < 4; r++)
        xcA[j][r] = xrow[xoff[j][r]];
    if (ug_ok) xhA = xrow[xhoff];
  }
#pragma unroll
  for (int j = 0; j < 2; j++)
#pragma unroll
    for (int r = 0; r < 4; r++) xcB[j][r] = 0.f;

  barrier_lds();

#pragma unroll 1
  for (int tb = 0; tb < 160; tb += 2) {
    SCAN_STEP(tb,     0, xcA, xhA, xcB, xhB);
    SCAN_STEP(tb + 1, 1, xcB, xhB, xcA, xhA);
  }
}
#undef SCAN_STEP

// ---------------------------------------------------------------------------
__global__ __launch_bounds__(256, 1) void fusion_kernel(
    const unsigned short* __restrict__ featbuf, const unsigned short* __restrict__ fwT,
    const float2* __restrict__ fepi, float* __restrict__ out)
{
  __shared__ unsigned short At[32 * 520];   // [m][k], stride 520 (pad)
  const int bx = blockIdx.x;
  const int b = bx / 800, mb = bx - b * 800;
  const long m0 = (long)mb * 32;            // hw base within batch
  const int tid = threadIdx.x, lane = tid & 63, wv = tid >> 6;
  const int ncol = lane & 15, kq = lane >> 4;

  const unsigned short* fp = featbuf + ((long)b * 25600 + m0) * 512;
#pragma unroll
  for (int rr = 0; rr < 8; rr++) {
    const int e = tid + rr * 256;
    const int m = e >> 6, kp = e & 63;
    *(bf16x8*)&At[m * 520 + kp * 8] = *(const bf16x8*)(fp + (long)m * 512 + kp * 8);
  }
  bf16x8 Bf[2][16];
  float2 fe[2];
#pragma unroll
  for (int j = 0; j < 2; j++) {
    const int o = (wv * 2 + j) * 16 + ncol;
    const unsigned short* wp = fwT + (long)o * 512;
#pragma unroll
    for (int kt = 0; kt < 16; kt++)
      Bf[j][kt] = *(const bf16x8*)(wp + kt * 32 + kq * 8);
    fe[j] = fepi[o];
  }
  __syncthreads();

  f32x4 acc[2][2];
#pragma unroll
  for (int mt = 0; mt < 2; mt++)
#pragma unroll
    for (int j = 0; j < 2; j++)
      acc[mt][j] = (f32x4){0.f, 0.f, 0.f, 0.f};
#pragma unroll
  for (int kt = 0; kt < 16; kt++) {
    const bf16x8 A0 = *(const bf16x8*)&At[ncol * 520 + kt * 32 + kq * 8];
    const bf16x8 A1 = *(const bf16x8*)&At[(16 + ncol) * 520 + kt * 32 + kq * 8];
    acc[0][0] = mfma16(A0, Bf[0][kt], acc[0][0]);
    acc[0][1] = mfma16(A0, Bf[1][kt], acc[0][1]);
    acc[1][0] = mfma16(A1, Bf[0][kt], acc[1][0]);
    acc[1][1] = mfma16(A1, Bf[1][kt], acc[1][1]);
  }
#pragma unroll
  for (int mt = 0; mt < 2; mt++)
#pragma unroll
    for (int j = 0; j < 2; j++) {
      const int o = (wv * 2 + j) * 16 + ncol;
      const long hw = m0 + mt * 16 + kq * 4;
      f32x4 v;
#pragma unroll
      for (int r = 0; r < 4; r++) {
        const float z = acc[mt][j][r] * fe[j].x + fe[j].y;
        v[r] = (z > 0.f) ? z : 0.f;
      }
      *(f32x4*)(out + ((long)(b * 128 + o)) * 25600 + hw) = v;  // NCHW, float4
    }
}

// ---------------------------------------------------------------------------
extern "C" void kernel_launch(void* const* d_in, const int* in_sizes, int n_in,
                              void* d_out, int out_size, void* d_ws, size_t ws_size,
                              hipStream_t stream)
{
  if (ws_size < (size_t)WS_TOTAL) return;  // fail visibly rather than corrupt

  const float* x        = (const float*)d_in[0];
  const float* kernels  = (const float*)d_in[1];
  const float* biases   = (const float*)d_in[2];
  const float* bn_gamma = (const float*)d_in[3];
  const float* bn_beta  = (const float*)d_in[4];
  const float* bn_mean  = (const float*)d_in[5];
  const float* bn_var   = (const float*)d_in[6];
  const float* prelu_a  = (const float*)d_in[7];
  const float* fus_w    = (const float*)d_in[8];
  const float* fus_b    = (const float*)d_in[9];
  const float* fbn_g    = (const float*)d_in[10];
  const float* fbn_b    = (const float*)d_in[11];
  const float* fbn_m    = (const float*)d_in[12];
  const float* fbn_v    = (const float*)d_in[13];

  char* ws = (char*)d_ws;
  float*          xT      = (float*)(ws + WS_XT);
  unsigned short* wprep   = (unsigned short*)(ws + WS_WPREP);
  float2*         epi     = (float2*)(ws + WS_EPI);
  unsigned short* fwT     = (unsigned short*)(ws + WS_FWT);
  float2*         fepi    = (float2*)(ws + WS_FEPI);
  unsigned short* featbuf = (unsigned short*)(ws + WS_FEAT);
  unsigned int*   ex      = (unsigned int*)(ws + WS_EX);
  float*          out     = (float*)d_out;

  prep_kernel<<<1027, 256, 0, stream>>>(kernels, biases, bn_gamma, bn_beta, bn_mean, bn_var,
                                        fus_w, fus_b, fbn_g, fbn_b, fbn_m, fbn_v,
                                        wprep, epi, fwT, fepi);
  transpose_kernel<<<dim3(20, 160, 8), 256, 0, stream>>>(x, xT);
  scan_kernel<<<160, 512, 0, stream>>>(xT, wprep, epi, prelu_a, featbuf, ex);
  fusion_kernel<<<6400, 256, 0, stream>>>(featbuf, fwT, fepi, out);
}